// Round 9
// baseline (190.809 us; speedup 1.0000x reference)
//
#include <hip/hip_runtime.h>
#include <hip/hip_bf16.h>

#define N2 16384
#define D  128
#define SQC1 1.69864360258810896f         // sqrt(2*log2(e)), folded into zn
#define LN2  0.69314718055994530942f

typedef __bf16 bf16x8 __attribute__((ext_vector_type(8)));
typedef float  f32x4  __attribute__((ext_vector_type(4)));

#if __has_builtin(__builtin_amdgcn_exp2f)
#define EXP2(x) __builtin_amdgcn_exp2f(x)
#else
#define EXP2(x) exp2f(x)
#endif

__device__ __forceinline__ unsigned short f2bf(float f) {
    union { float f; unsigned u; } v; v.f = f;
    unsigned r = v.u + 0x7fffu + ((v.u >> 16) & 1u);
    return (unsigned short)(r >> 16);
}

// ---------- kernel 1: row L2-normalize -> bf16 sqrt(C1)*zn, + zero rowsum/out ----------
__global__ void k_norm(const float* __restrict__ z, unsigned short* __restrict__ zn,
                       float* __restrict__ rowsum, float* __restrict__ out) {
    if (blockIdx.x < 64) rowsum[blockIdx.x * 256 + threadIdx.x] = 0.f;
    if (blockIdx.x == 64 && threadIdx.x == 0) out[0] = 0.f;
    int row  = blockIdx.x * 4 + (threadIdx.x >> 6);
    int lane = threadIdx.x & 63;
    const float2 v = ((const float2*)(z + (size_t)row * D))[lane];
    float ss = v.x * v.x + v.y * v.y;
    #pragma unroll
    for (int m = 1; m < 64; m <<= 1) ss += __shfl_xor(ss, m);
    float inv = SQC1 / fmaxf(sqrtf(ss), 1e-12f);
    ushort2 o; o.x = f2bf(v.x * inv); o.y = f2bf(v.y * inv);
    ((ushort2*)(zn + (size_t)row * D))[lane] = o;
}

// ---------- kernel 2: barrier-free, LDS-free symmetric sim + exp sums ----------
// 4096 independent wave-jobs (1024 blocks x 4 waves = 4 blocks/CU, 16 waves/CU).
// Job = (ti: 64-row stripe [0,256), chunk [0,16)). Wave holds A(ti) in regs;
// sweeps s in [8c, 8c+8) (chunk 15 adds s=128 when ti<128); B-subtile
// (jt=(ti+s)&255, 64x128) loaded global->reg each step (zn is 4 MB,
// L2-resident). s=0: diagonal, mask li==lj, row sums only. s>0: row sums
// (regs) + col sums (atomics, by symmetry). No barriers -> waves de-phase
// freely; 4 waves/SIMD hide L2 latency under MFMA + epilogue VALU.
__global__ __launch_bounds__(256, 4)
void k_sim(const unsigned short* __restrict__ zn, float* __restrict__ rowsum) {
    const int wid = threadIdx.x >> 6, lane = threadIdx.x & 63;
    const int job = blockIdx.x * 4 + wid;            // 0..4095
    const int ti = job >> 4;                         // 64-row stripe [0,256)
    const int chunk = job & 15;
    const int sLo = chunk * 8;
    const int nt = (chunk == 15 && ti < 128) ? 9 : 8;
    const int l16 = lane & 15, lg = lane >> 4;
    const char* znb = (const char*)zn;
    const f32x4 ZERO = {0.f, 0.f, 0.f, 0.f};

    // per-lane base byte offset within a 64x256B stripe (row=l16, kchunk=lg)
    const int laneoff = l16 * 256 + lg * 16;

    // A fragments: 64 rows x 128 k -> 16 x bf16x8 (one L2 read, reused nt steps)
    bf16x8 af[4][4];                                 // [kk][m]
    {
        const char* ab = znb + (size_t)ti * 16384 + laneoff;
        #pragma unroll
        for (int kk = 0; kk < 4; ++kk)
            #pragma unroll
            for (int m = 0; m < 4; ++m)
                af[kk][m] = *(const bf16x8*)(ab + m * 4096 + kk * 64);
    }

    float rs[4][4];
    #pragma unroll
    for (int m = 0; m < 4; ++m)
        #pragma unroll
        for (int r = 0; r < 4; ++r) rs[m][r] = 0.f;

    for (int t = 0; t < nt; ++t) {
        const int s  = sLo + t;
        const int jt = (ti + s) & 255;
        const char* bb = znb + (size_t)jt * 16384 + laneoff;

        bf16x8 bfr[4][4];                            // [kk][n]
        #pragma unroll
        for (int kk = 0; kk < 4; ++kk)
            #pragma unroll
            for (int n = 0; n < 4; ++n)
                bfr[kk][n] = *(const bf16x8*)(bb + n * 4096 + kk * 64);

        f32x4 acc[4][4];
        __builtin_amdgcn_s_setprio(1);
        #pragma unroll
        for (int m = 0; m < 4; ++m)
            #pragma unroll
            for (int n = 0; n < 4; ++n)
                acc[m][n] = __builtin_amdgcn_mfma_f32_16x16x32_bf16(af[0][m], bfr[0][n], ZERO, 0, 0, 0);
        #pragma unroll
        for (int kk = 1; kk < 4; ++kk)
            #pragma unroll
            for (int m = 0; m < 4; ++m)
                #pragma unroll
                for (int n = 0; n < 4; ++n)
                    acc[m][n] = __builtin_amdgcn_mfma_f32_16x16x32_bf16(af[kk][m], bfr[kk][n], acc[m][n], 0, 0, 0);
        __builtin_amdgcn_s_setprio(0);

        // epilogue: e = exp2(acc) = exp(sim)
        if (s == 0) {
            // diagonal subtile: mask self-sim, row sums only
            #pragma unroll
            for (int m = 0; m < 4; ++m)
                #pragma unroll
                for (int r = 0; r < 4; ++r) {
                    int li = m * 16 + lg * 4 + r;
                    float a = 0.f;
                    #pragma unroll
                    for (int n = 0; n < 4; ++n) {
                        int lj = n * 16 + l16;
                        float e = EXP2(acc[m][n][r]);
                        a += (li == lj) ? 0.f : e;
                    }
                    rs[m][r] += a;
                }
        } else {
            float cs[4] = {0.f, 0.f, 0.f, 0.f};
            #pragma unroll
            for (int m = 0; m < 4; ++m)
                #pragma unroll
                for (int r = 0; r < 4; ++r) {
                    float a = 0.f;
                    #pragma unroll
                    for (int n = 0; n < 4; ++n) {
                        float e = EXP2(acc[m][n][r]);
                        a += e;
                        cs[n] += e;
                    }
                    rs[m][r] += a;
                }
            // column sums: reduce over the 4 lg row-groups, one atomic per col
            #pragma unroll
            for (int n = 0; n < 4; ++n) {
                float v = cs[n];
                v += __shfl_xor(v, 16);
                v += __shfl_xor(v, 32);
                if (lg == 0)
                    atomicAdd(&rowsum[jt * 64 + n * 16 + l16], v);
            }
        }
    }

    // row-sum flush: reduce across the 16 column-lanes, one atomic per row
    #pragma unroll
    for (int m = 0; m < 4; ++m)
        #pragma unroll
        for (int r = 0; r < 4; ++r) {
            float v = rs[m][r];
            v += __shfl_xor(v, 1);
            v += __shfl_xor(v, 2);
            v += __shfl_xor(v, 4);
            v += __shfl_xor(v, 8);
            if (l16 == 0)
                atomicAdd(&rowsum[ti * 64 + m * 16 + lg * 4 + r], v);
        }
}

// ---------- kernel 3: fused loss + mean ----------
// mean loss = (1/N2) * [ sum_i ln(rowsum_i) - ln2 * sum_{i,k} zn'[i][k]*zn'[i^1][k] ]
__global__ void k_loss_reduce(const unsigned short* __restrict__ zn,
                              const float* __restrict__ rowsum,
                              float* __restrict__ out) {
    const int tid = threadIdx.x + blockIdx.x * 256;   // 64 blocks x 256
    float p = 0.f;
    const bf16x8* v8 = (const bf16x8*)zn;
    for (int v = tid; v < N2 * D / 8; v += 64 * 256) {
        bf16x8 a = v8[v];
        bf16x8 b = v8[v ^ 16];                        // row i^1, same k-slice
        #pragma unroll
        for (int e = 0; e < 8; ++e) p += (float)a[e] * (float)b[e];
    }
    float part = logf(rowsum[tid]) - LN2 * p;         // exactly one row per thread

    __shared__ float sm[4];
    #pragma unroll
    for (int m = 1; m < 64; m <<= 1) part += __shfl_xor(part, m);
    if ((threadIdx.x & 63) == 0) sm[threadIdx.x >> 6] = part;
    __syncthreads();
    if (threadIdx.x == 0)
        atomicAdd(out, (sm[0] + sm[1] + sm[2] + sm[3]) * (1.0f / (float)N2));
}

extern "C" void kernel_launch(void* const* d_in, const int* in_sizes, int n_in,
                              void* d_out, int out_size, void* d_ws, size_t ws_size,
                              hipStream_t stream) {
    const float* z = (const float*)d_in[0];
    float* out = (float*)d_out;

    unsigned short* zn = (unsigned short*)d_ws;                       // 4 MiB
    float* rowsum = (float*)((char*)d_ws + (size_t)N2 * D * 2);       // 64 KiB

    k_norm<<<N2 / 4, 256, 0, stream>>>(z, zn, rowsum, out);
    k_sim<<<1024, 256, 0, stream>>>(zn, rowsum);
    k_loss_reduce<<<64, 256, 0, stream>>>(zn, rowsum, out);
}

// Round 10
// 79.243 us; speedup vs baseline: 2.4079x; 2.4079x over previous
//
#include <hip/hip_runtime.h>
#include <hip/hip_bf16.h>

#define N2 16384
#define D  128
#define PANEL 32768                       // bytes per 128x128 bf16 panel
#define SQC1 1.69864360258810896f         // sqrt(2*log2(e)), folded into zn
#define LN2  0.69314718055994530942f

typedef __bf16 bf16x8 __attribute__((ext_vector_type(8)));
typedef float  f32x4  __attribute__((ext_vector_type(4)));

#if __has_builtin(__builtin_amdgcn_exp2f)
#define EXP2(x) __builtin_amdgcn_exp2f(x)
#else
#define EXP2(x) exp2f(x)
#endif

__device__ __forceinline__ unsigned short f2bf(float f) {
    union { float f; unsigned u; } v; v.f = f;
    unsigned r = v.u + 0x7fffu + ((v.u >> 16) & 1u);
    return (unsigned short)(r >> 16);
}

// stage one 32KB panel global->LDS, 8 waves x 4 x global_load_lds(16B).
// LDS dest linear; XOR swizzle on the GLOBAL source (involution); reads
// use byte ^ ((row&7)<<4), row = byte>>8. (rule #21)
__device__ __forceinline__ void stage8(const char* __restrict__ g,
                                       char* lds, int tid) {
    const int wid = tid >> 6, lane = tid & 63;
    #pragma unroll
    for (int i = 0; i < 4; ++i) {
        int off = (wid << 12) + (i << 10) + (lane << 4);
        int src = off ^ (((off >> 8) & 7) << 4);
        __builtin_amdgcn_global_load_lds(
            (const __attribute__((address_space(1))) unsigned*)(g + src),
            (__attribute__((address_space(3))) unsigned*)(lds + (wid << 12) + (i << 10)),
            16, 0, 0);
    }
}

// ---------- kernel 1: row L2-normalize -> bf16 sqrt(C1)*zn, + zero rowsum/out ----------
__global__ void k_norm(const float* __restrict__ z, unsigned short* __restrict__ zn,
                       float* __restrict__ rowsum, float* __restrict__ out) {
    if (blockIdx.x < 64) rowsum[blockIdx.x * 256 + threadIdx.x] = 0.f;
    if (blockIdx.x == 64 && threadIdx.x == 0) out[0] = 0.f;
    int row  = blockIdx.x * 4 + (threadIdx.x >> 6);
    int lane = threadIdx.x & 63;
    const float2 v = ((const float2*)(z + (size_t)row * D))[lane];
    float ss = v.x * v.x + v.y * v.y;
    #pragma unroll
    for (int m = 1; m < 64; m <<= 1) ss += __shfl_xor(ss, m);
    float inv = SQC1 / fmaxf(sqrtf(ss), 1e-12f);
    ushort2 o; o.x = f2bf(v.x * inv); o.y = f2bf(v.y * inv);
    ((ushort2*)(zn + (size_t)row * D))[lane] = o;
}

// ---------- kernel 2: symmetric fused sim GEMM + exp row/col sums ----------
// 8-wave blocks (512 thr), wave grid 4x2, wave tile 32x64 -> ~115 regs/wave
// so 2 blocks/CU = 4 waves/SIMD (vs R3's 2). R3's 2-barrier dbuf skeleton.
// Col atomics flushed at next-tile top AFTER stage issue: vmcnt(8) leaves
// {4 stage + 4 atomics} in flight, drains only stage(t) -> no RMW stall.
__global__ __launch_bounds__(512, 4)
void k_sim(const unsigned short* __restrict__ zn, float* __restrict__ rowsum) {
    __shared__ char ls[2 * PANEL];        // 64KB: A prologue via ls0, then B dbuf
    char* ls0 = ls;
    char* ls1 = ls + PANEL;

    const int tileI = blockIdx.y;
    const int c = blockIdx.x;
    const int sLo = c * 16;
    const int nt = (c == 3 && tileI < 64) ? 17 : 16;

    const int tid  = threadIdx.x;
    const int lane = tid & 63, wid = tid >> 6;
    const int wr = wid >> 1, wc = wid & 1;          // 4x2 waves: 32 rows x 64 cols
    const int l16 = lane & 15, lg = lane >> 4;
    const char* znb = (const char*)zn;
    const f32x4 ZERO = {0.f, 0.f, 0.f, 0.f};

    // prologue: stage A(ti) -> ls0, pull A fragments (32 rows) to registers
    stage8(znb + (size_t)tileI * PANEL, ls0, tid);
    asm volatile("s_waitcnt vmcnt(0)" ::: "memory");
    __builtin_amdgcn_s_barrier();

    bf16x8 af[4][2];                                   // [kk][m], 32 VGPR
    #pragma unroll
    for (int kk = 0; kk < 4; ++kk)
        #pragma unroll
        for (int m = 0; m < 2; ++m) {
            int row = wr * 32 + m * 16 + l16;
            int d = row * 256 + kk * 64 + lg * 16;
            af[kk][m] = *(const bf16x8*)(ls0 + (d ^ ((row & 7) << 4)));
        }
    asm volatile("s_waitcnt lgkmcnt(0)" ::: "memory");
    __builtin_amdgcn_s_barrier();                      // ls0 free for B

    stage8(znb + (size_t)((tileI + sLo) & 127) * PANEL, ls0, tid);  // B(sLo)

    float rs[2][4];
    #pragma unroll
    for (int m = 0; m < 2; ++m)
        #pragma unroll
        for (int r = 0; r < 4; ++r) rs[m][r] = 0.f;
    float csp[4] = {0.f, 0.f, 0.f, 0.f};               // prev tile col sums (reduced)
    int jtp = tileI;                                   // dummy first flush adds 0.0

    for (int t = 0; t < nt; ++t) {
        const int s  = sLo + t;
        const int jt = (tileI + s) & 127;
        char* rbuf = (t & 1) ? ls1 : ls0;
        char* sbuf = (t & 1) ? ls0 : ls1;

        // a) prefetch next B panel (4 loads/wave)
        if (t + 1 < nt)
            stage8(znb + (size_t)((tileI + s + 1) & 127) * PANEL, sbuf, tid);
        // b) flush PREVIOUS tile's col sums (4 atomic instrs/wave, lg==0 lanes)
        #pragma unroll
        for (int n = 0; n < 4; ++n)
            if (lg == 0)
                atomicAdd(&rowsum[jtp * 128 + wc * 64 + n * 16 + l16], csp[n]);
        // c) drain stage(t) only: 8 newest (4 stage + 4 atomics) stay in flight
        if (t + 1 < nt) { asm volatile("s_waitcnt vmcnt(8)" ::: "memory"); }
        else           { asm volatile("s_waitcnt vmcnt(4)" ::: "memory"); }
        __builtin_amdgcn_s_barrier();                  // barrier1: B(t) visible

        // K-loop: per-kk B frags (16 transient regs), 8 MFMA each
        f32x4 acc[2][4];
        bf16x8 bfr[4];
        #pragma unroll
        for (int kk = 0; kk < 3; ++kk) {
            #pragma unroll
            for (int n = 0; n < 4; ++n) {
                int row = wc * 64 + n * 16 + l16;
                int d = row * 256 + kk * 64 + lg * 16;
                bfr[n] = *(const bf16x8*)(rbuf + (d ^ ((row & 7) << 4)));
            }
            #pragma unroll
            for (int m = 0; m < 2; ++m)
                #pragma unroll
                for (int n = 0; n < 4; ++n)
                    acc[m][n] = __builtin_amdgcn_mfma_f32_16x16x32_bf16(
                        af[kk][m], bfr[n], (kk == 0) ? ZERO : acc[m][n], 0, 0, 0);
        }
        // kk=3: issue reads, certify rbuf free (barrier2), THEN mfma+epilogue
        #pragma unroll
        for (int n = 0; n < 4; ++n) {
            int row = wc * 64 + n * 16 + l16;
            int d = row * 256 + 3 * 64 + lg * 16;
            bfr[n] = *(const bf16x8*)(rbuf + (d ^ ((row & 7) << 4)));
        }
        asm volatile("s_waitcnt lgkmcnt(0)" ::: "memory");
        __builtin_amdgcn_s_barrier();                  // barrier2: rbuf reusable
        #pragma unroll
        for (int m = 0; m < 2; ++m)
            #pragma unroll
            for (int n = 0; n < 4; ++n)
                acc[m][n] = __builtin_amdgcn_mfma_f32_16x16x32_bf16(
                    af[3][m], bfr[n], acc[m][n], 0, 0, 0);

        // epilogue (sync-free window): e = exp2(acc) = exp(sim)
        if (s == 0) {
            // diagonal tile: mask self-sim, row sums only; csp stays 0
            #pragma unroll
            for (int m = 0; m < 2; ++m)
                #pragma unroll
                for (int r = 0; r < 4; ++r) {
                    int li = wr * 32 + m * 16 + lg * 4 + r;
                    float a = 0.f;
                    #pragma unroll
                    for (int n = 0; n < 4; ++n) {
                        int lj = wc * 64 + n * 16 + l16;
                        float e = EXP2(acc[m][n][r]);
                        a += (li == lj) ? 0.f : e;
                    }
                    rs[m][r] += a;
                }
            jtp = tileI;
        } else {
            float cs[4] = {0.f, 0.f, 0.f, 0.f};
            #pragma unroll
            for (int m = 0; m < 2; ++m)
                #pragma unroll
                for (int r = 0; r < 4; ++r) {
                    float a = 0.f;
                    #pragma unroll
                    for (int n = 0; n < 4; ++n) {
                        float e = EXP2(acc[m][n][r]);
                        a += e;
                        cs[n] += e;
                    }
                    rs[m][r] += a;
                }
            // reduce col partials over the 4 lg row-groups now; flush next top
            #pragma unroll
            for (int n = 0; n < 4; ++n) {
                float v = cs[n];
                v += __shfl_xor(v, 16);
                v += __shfl_xor(v, 32);
                csp[n] = v;
            }
            jtp = jt;
        }
    }

    // final flush: last tile's col sums + row sums
    #pragma unroll
    for (int n = 0; n < 4; ++n)
        if (lg == 0)
            atomicAdd(&rowsum[jtp * 128 + wc * 64 + n * 16 + l16], csp[n]);
    #pragma unroll
    for (int m = 0; m < 2; ++m)
        #pragma unroll
        for (int r = 0; r < 4; ++r) {
            float v = rs[m][r];
            v += __shfl_xor(v, 1);
            v += __shfl_xor(v, 2);
            v += __shfl_xor(v, 4);
            v += __shfl_xor(v, 8);
            if (l16 == 0)
                atomicAdd(&rowsum[tileI * 128 + wr * 32 + m * 16 + lg * 4 + r], v);
        }
}

// ---------- kernel 3: fused loss + mean ----------
// mean loss = (1/N2) * [ sum_i ln(rowsum_i) - ln2 * sum_{i,k} zn'[i][k]*zn'[i^1][k] ]
__global__ void k_loss_reduce(const unsigned short* __restrict__ zn,
                              const float* __restrict__ rowsum,
                              float* __restrict__ out) {
    const int tid = threadIdx.x + blockIdx.x * 256;   // 64 blocks x 256
    float p = 0.f;
    const bf16x8* v8 = (const bf16x8*)zn;
    for (int v = tid; v < N2 * D / 8; v += 64 * 256) {
        bf16x8 a = v8[v];
        bf16x8 b = v8[v ^ 16];                        // row i^1, same k-slice
        #pragma unroll
        for (int e = 0; e < 8; ++e) p += (float)a[e] * (float)b[e];
    }
    float part = logf(rowsum[tid]) - LN2 * p;         // exactly one row per thread

    __shared__ float sm[4];
    #pragma unroll
    for (int m = 1; m < 64; m <<= 1) part += __shfl_xor(part, m);
    if ((threadIdx.x & 63) == 0) sm[threadIdx.x >> 6] = part;
    __syncthreads();
    if (threadIdx.x == 0)
        atomicAdd(out, (sm[0] + sm[1] + sm[2] + sm[3]) * (1.0f / (float)N2));
}

extern "C" void kernel_launch(void* const* d_in, const int* in_sizes, int n_in,
                              void* d_out, int out_size, void* d_ws, size_t ws_size,
                              hipStream_t stream) {
    const float* z = (const float*)d_in[0];
    float* out = (float*)d_out;

    unsigned short* zn = (unsigned short*)d_ws;                       // 4 MiB
    float* rowsum = (float*)((char*)d_ws + (size_t)N2 * D * 2);       // 64 KiB

    k_norm<<<N2 / 4, 256, 0, stream>>>(z, zn, rowsum, out);
    dim3 grid(4, 128);                                                // s-chunks x i-tiles
    k_sim<<<grid, 512, 0, stream>>>(zn, rowsum);
    k_loss_reduce<<<64, 256, 0, stream>>>(zn, rowsum, out);
}

// Round 11
// 68.301 us; speedup vs baseline: 2.7936x; 1.1602x over previous
//
#include <hip/hip_runtime.h>
#include <hip/hip_bf16.h>

#define N2 16384
#define D  128
#define PANEL 32768                       // bytes per 128x128 bf16 panel
#define HPAN  16384                       // bytes per 64-row half panel
#define SQC1 1.69864360258810896f         // sqrt(2*log2(e)), folded into zn
#define LN2  0.69314718055994530942f

typedef __bf16 bf16x8 __attribute__((ext_vector_type(8)));
typedef float  f32x4  __attribute__((ext_vector_type(4)));

#if __has_builtin(__builtin_amdgcn_exp2f)
#define EXP2(x) __builtin_amdgcn_exp2f(x)
#else
#define EXP2(x) exp2f(x)
#endif

__device__ __forceinline__ unsigned short f2bf(float f) {
    union { float f; unsigned u; } v; v.f = f;
    unsigned r = v.u + 0x7fffu + ((v.u >> 16) & 1u);
    return (unsigned short)(r >> 16);
}

// stage a full 32KB panel: 8 x global_load_lds(16B)/thread. LDS dest linear;
// XOR swizzle on the GLOBAL source (involution); reads use byte^((row&7)<<4),
// row = byte>>8. (rule #21)
__device__ __forceinline__ void stage32(const char* __restrict__ g,
                                        char* lds, int tid) {
    const int wid = tid >> 6, lane = tid & 63;
    #pragma unroll
    for (int i = 0; i < 8; ++i) {
        int off = (wid << 13) + (i << 10) + (lane << 4);
        int src = off ^ (((off >> 8) & 7) << 4);
        __builtin_amdgcn_global_load_lds(
            (const __attribute__((address_space(1))) unsigned*)(g + src),
            (__attribute__((address_space(3))) unsigned*)(lds + (wid << 13) + (i << 10)),
            16, 0, 0);
    }
}

// stage a 16KB half panel (64 rows): 4 x global_load_lds(16B)/thread
__device__ __forceinline__ void stage16(const char* __restrict__ g,
                                        char* lds, int tid) {
    const int wid = tid >> 6, lane = tid & 63;
    #pragma unroll
    for (int i = 0; i < 4; ++i) {
        int off = (wid << 12) + (i << 10) + (lane << 4);
        int src = off ^ (((off >> 8) & 7) << 4);
        __builtin_amdgcn_global_load_lds(
            (const __attribute__((address_space(1))) unsigned*)(g + src),
            (__attribute__((address_space(3))) unsigned*)(lds + (wid << 12) + (i << 10)),
            16, 0, 0);
    }
}

// ---------- kernel 1: row L2-normalize -> bf16 sqrt(C1)*zn, + zero rowsum/out ----------
__global__ void k_norm(const float* __restrict__ z, unsigned short* __restrict__ zn,
                       float* __restrict__ rowsum, float* __restrict__ out) {
    if (blockIdx.x < 64) rowsum[blockIdx.x * 256 + threadIdx.x] = 0.f;
    if (blockIdx.x == 64 && threadIdx.x == 0) out[0] = 0.f;
    int row  = blockIdx.x * 4 + (threadIdx.x >> 6);
    int lane = threadIdx.x & 63;
    const float2 v = ((const float2*)(z + (size_t)row * D))[lane];
    float ss = v.x * v.x + v.y * v.y;
    #pragma unroll
    for (int m = 1; m < 64; m <<= 1) ss += __shfl_xor(ss, m);
    float inv = SQC1 / fmaxf(sqrtf(ss), 1e-12f);
    ushort2 o; o.x = f2bf(v.x * inv); o.y = f2bf(v.y * inv);
    ((ushort2*)(zn + (size_t)row * D))[lane] = o;
}

// ---------- kernel 2: symmetric fused sim GEMM + exp row/col sums ----------
// block (c, ti): tiles s in [11c, 11c+11) (c==5: 9 or 10 incl. s=64 for ti<64),
// each 128x128 tile processed as TWO 64-col steps (q = 2 per tile).
// Wave grid 2x2; wave tile 64 rows x 32 cols -> acc 32 regs; af 64; bfr 8
// transient -> ~140 unified regs -> 3 waves/SIMD at launch_bounds(256,3).
// ONE barrier per step: {vmcnt(2); barrier; stage(q+1); flush csp; ds_read;
// MFMA; epilogue}. Stage-issue after the barrier cannot race prior readers
// (their reads were consumed by MFMAs before they reached this barrier).
// vmcnt(2) drains the 4 stage loads, leaves the 2 col atomics in flight.
__global__ __launch_bounds__(256, 3)
void k_sim(const unsigned short* __restrict__ zn, float* __restrict__ rowsum) {
    __shared__ char ls[PANEL];            // 32KB: A transit, then 2x16KB B dbuf
    char* ls0 = ls;
    char* ls1 = ls + HPAN;

    const int tileI = blockIdx.y;
    const int c = blockIdx.x;
    const int sLo = c * 11;
    const int ntile = (c < 5) ? 11 : ((tileI < 64) ? 10 : 9);
    const int nq = ntile * 2;

    const int tid  = threadIdx.x;
    const int lane = tid & 63, wid = tid >> 6;
    const int wr = wid >> 1, wc = wid & 1;          // 2x2 waves
    const int l16 = lane & 15, lg = lane >> 4;
    const char* znb = (const char*)zn;
    const f32x4 ZERO = {0.f, 0.f, 0.f, 0.f};

    // prologue: stage A(ti) through LDS, pull fragments to registers
    stage32(znb + (size_t)tileI * PANEL, ls, tid);
    asm volatile("s_waitcnt vmcnt(0)" ::: "memory");
    __builtin_amdgcn_s_barrier();

    bf16x8 af[4][4];                                   // [kk][m], 64 VGPR
    #pragma unroll
    for (int kk = 0; kk < 4; ++kk)
        #pragma unroll
        for (int m = 0; m < 4; ++m) {
            int row = wr * 64 + m * 16 + l16;
            int d = row * 256 + kk * 64 + lg * 16;
            af[kk][m] = *(const bf16x8*)(ls + (d ^ ((row & 7) << 4)));
        }
    asm volatile("s_waitcnt lgkmcnt(0)" ::: "memory");
    __builtin_amdgcn_s_barrier();                      // LDS free for B dbuf

    // stage B(q=0): tile sLo, half 0 -> ls0
    stage16(znb + (size_t)((tileI + sLo) & 127) * PANEL, ls0, tid);

    float rs[4][4];
    #pragma unroll
    for (int m = 0; m < 4; ++m)
        #pragma unroll
        for (int r = 0; r < 4; ++r) rs[m][r] = 0.f;
    float csp0 = 0.f, csp1 = 0.f;                      // prev step col sums (reduced)
    int jcp = tileI * 128 + wc * 32;                   // dummy first flush (+0.0)

    for (int q = 0; q < nq; ++q) {
        const int s  = sLo + (q >> 1);
        const int h  = q & 1;
        const int jt = (tileI + s) & 127;
        char* rbuf = (q & 1) ? ls1 : ls0;
        char* sbuf = (q & 1) ? ls0 : ls1;

        // single sync point: drain stage(q) (4 oldest VM ops), keep atomics flying
        if (q) { asm volatile("s_waitcnt vmcnt(2)" ::: "memory"); }
        else   { asm volatile("s_waitcnt vmcnt(0)" ::: "memory"); }
        __builtin_amdgcn_s_barrier();

        // issue next stage (safe: prior readers of sbuf passed the barrier)
        if (q + 1 < nq) {
            const int s1 = sLo + ((q + 1) >> 1);
            const int h1 = (q + 1) & 1;
            stage16(znb + (size_t)((tileI + s1) & 127) * PANEL + h1 * HPAN,
                    sbuf, tid);
        }
        // flush previous step's column sums (2 atomics, 2 steps of cover)
        if (lg == 0) {
            atomicAdd(&rowsum[jcp + l16], csp0);
            atomicAdd(&rowsum[jcp + 16 + l16], csp1);
        }

        // compute (sync-free): per-kk B frags + 8 MFMA
        f32x4 acc[4][2];
        bf16x8 bfr[2];
        #pragma unroll
        for (int kk = 0; kk < 4; ++kk) {
            #pragma unroll
            for (int n = 0; n < 2; ++n) {
                int row = wc * 32 + n * 16 + l16;      // row in 64-row half panel
                int d = row * 256 + kk * 64 + lg * 16;
                bfr[n] = *(const bf16x8*)(rbuf + (d ^ ((row & 7) << 4)));
            }
            #pragma unroll
            for (int m = 0; m < 4; ++m)
                #pragma unroll
                for (int n = 0; n < 2; ++n)
                    acc[m][n] = __builtin_amdgcn_mfma_f32_16x16x32_bf16(
                        af[kk][m], bfr[n], (kk == 0) ? ZERO : acc[m][n], 0, 0, 0);
        }

        // epilogue: e = exp2(acc) = exp(sim)
        if (s == 0) {
            // diagonal tile: mask self-sim, row sums only
            #pragma unroll
            for (int m = 0; m < 4; ++m)
                #pragma unroll
                for (int r = 0; r < 4; ++r) {
                    int li = wr * 64 + m * 16 + lg * 4 + r;
                    float a = 0.f;
                    #pragma unroll
                    for (int n = 0; n < 2; ++n) {
                        int lj = h * 64 + wc * 32 + n * 16 + l16;
                        float e = EXP2(acc[m][n][r]);
                        a += (li == lj) ? 0.f : e;
                    }
                    rs[m][r] += a;
                }
            csp0 = csp1 = 0.f;
            jcp = jt * 128 + h * 64 + wc * 32;         // +0.0 flush, harmless
        } else {
            float cs0 = 0.f, cs1 = 0.f;
            #pragma unroll
            for (int m = 0; m < 4; ++m)
                #pragma unroll
                for (int r = 0; r < 4; ++r) {
                    float e0 = EXP2(acc[m][0][r]);
                    float e1 = EXP2(acc[m][1][r]);
                    rs[m][r] += e0 + e1;
                    cs0 += e0; cs1 += e1;
                }
            // reduce col partials across the 4 lg row-groups now; flush next step
            cs0 += __shfl_xor(cs0, 16); cs0 += __shfl_xor(cs0, 32);
            cs1 += __shfl_xor(cs1, 16); cs1 += __shfl_xor(cs1, 32);
            csp0 = cs0; csp1 = cs1;
            jcp = jt * 128 + h * 64 + wc * 32;
        }
    }

    // final flush: last step's col sums + row sums
    if (lg == 0) {
        atomicAdd(&rowsum[jcp + l16], csp0);
        atomicAdd(&rowsum[jcp + 16 + l16], csp1);
    }
    #pragma unroll
    for (int m = 0; m < 4; ++m)
        #pragma unroll
        for (int r = 0; r < 4; ++r) {
            float v = rs[m][r];
            v += __shfl_xor(v, 1);
            v += __shfl_xor(v, 2);
            v += __shfl_xor(v, 4);
            v += __shfl_xor(v, 8);
            if (l16 == 0)
                atomicAdd(&rowsum[tileI * 128 + wr * 64 + m * 16 + lg * 4 + r], v);
        }
}

// ---------- kernel 3: fused loss + mean ----------
// mean loss = (1/N2) * [ sum_i ln(rowsum_i) - ln2 * sum_{i,k} zn'[i][k]*zn'[i^1][k] ]
__global__ void k_loss_reduce(const unsigned short* __restrict__ zn,
                              const float* __restrict__ rowsum,
                              float* __restrict__ out) {
    const int tid = threadIdx.x + blockIdx.x * 256;   // 64 blocks x 256
    float p = 0.f;
    const bf16x8* v8 = (const bf16x8*)zn;
    for (int v = tid; v < N2 * D / 8; v += 64 * 256) {
        bf16x8 a = v8[v];
        bf16x8 b = v8[v ^ 16];                        // row i^1, same k-slice
        #pragma unroll
        for (int e = 0; e < 8; ++e) p += (float)a[e] * (float)b[e];
    }
    float part = logf(rowsum[tid]) - LN2 * p;         // exactly one row per thread

    __shared__ float sm[4];
    #pragma unroll
    for (int m = 1; m < 64; m <<= 1) part += __shfl_xor(part, m);
    if ((threadIdx.x & 63) == 0) sm[threadIdx.x >> 6] = part;
    __syncthreads();
    if (threadIdx.x == 0)
        atomicAdd(out, (sm[0] + sm[1] + sm[2] + sm[3]) * (1.0f / (float)N2));
}

extern "C" void kernel_launch(void* const* d_in, const int* in_sizes, int n_in,
                              void* d_out, int out_size, void* d_ws, size_t ws_size,
                              hipStream_t stream) {
    const float* z = (const float*)d_in[0];
    float* out = (float*)d_out;

    unsigned short* zn = (unsigned short*)d_ws;                       // 4 MiB
    float* rowsum = (float*)((char*)d_ws + (size_t)N2 * D * 2);       // 64 KiB

    k_norm<<<N2 / 4, 256, 0, stream>>>(z, zn, rowsum, out);
    dim3 grid(6, 128);                                                // s-chunks x i-tiles
    k_sim<<<grid, 256, 0, stream>>>(zn, rowsum);
    k_loss_reduce<<<64, 256, 0, stream>>>(zn, rowsum, out);
}